// Round 2
// baseline (430.231 us; speedup 1.0000x reference)
//
#include <hip/hip_runtime.h>

#define IN_F  64
#define MID_F 128
#define OUT_F 32
#define SEGS_PER_BLK 64

typedef __bf16 bf16x8 __attribute__((ext_vector_type(8)));
typedef __bf16 bf16x4 __attribute__((ext_vector_type(4)));
typedef float  f32x4  __attribute__((ext_vector_type(4)));

static __device__ inline unsigned pack2(float a, float b) {
    unsigned short x = __builtin_bit_cast(unsigned short, (__bf16)a);
    unsigned short y = __builtin_bit_cast(unsigned short, (__bf16)b);
    return (unsigned)x | ((unsigned)y << 16);
}

// ---------------- CSR build ----------------
__global__ void hist_kernel(const int* __restrict__ sidx, unsigned* __restrict__ counts, int n) {
    int i = blockIdx.x * blockDim.x + threadIdx.x;
    int stride = gridDim.x * blockDim.x;
    for (; i < n; i += stride) atomicAdd(&counts[sidx[i]], 1u);
}

__global__ void scan1_kernel(const unsigned* __restrict__ counts, unsigned* __restrict__ offsets,
                             unsigned* __restrict__ bsum, int nsegP) {
    __shared__ unsigned s[1024];
    const int t = threadIdx.x;
    const int idx = blockIdx.x * 1024 + t;
    unsigned v = (idx < nsegP) ? counts[idx] : 0u;
    s[t] = v; __syncthreads();
    for (int o = 1; o < 1024; o <<= 1) {
        unsigned u = (t >= o) ? s[t - o] : 0u;
        __syncthreads();
        s[t] += u;
        __syncthreads();
    }
    if (idx < nsegP) offsets[idx] = s[t] - v;       // exclusive
    if (t == 1023) bsum[blockIdx.x] = s[1023];      // block total
}

__global__ void scan2_kernel(unsigned* __restrict__ bsum, int nb) {
    __shared__ unsigned s[1024];
    const int t = threadIdx.x;
    unsigned v = (t < nb) ? bsum[t] : 0u;
    s[t] = v; __syncthreads();
    for (int o = 1; o < 1024; o <<= 1) {
        unsigned u = (t >= o) ? s[t - o] : 0u;
        __syncthreads();
        s[t] += u;
        __syncthreads();
    }
    if (t < nb) bsum[t] = s[t] - v;                 // exclusive, in place
}

__global__ void scan3_kernel(unsigned* __restrict__ offsets, const unsigned* __restrict__ bsum,
                             int nsegP, int nrows) {
    int idx = blockIdx.x * 1024 + threadIdx.x;
    if (idx < nsegP) offsets[idx] += bsum[blockIdx.x];
    if (blockIdx.x == 0 && threadIdx.x == 0) offsets[nsegP] = (unsigned)nrows;
}

__global__ void scatter_kernel(const int* __restrict__ sidx, const unsigned* __restrict__ offsets,
                               unsigned* __restrict__ cursors, unsigned* __restrict__ rowids, int n) {
    int i = blockIdx.x * blockDim.x + threadIdx.x;
    int stride = gridDim.x * blockDim.x;
    for (; i < n; i += stride) {
        int s = sidx[i];
        unsigned p = offsets[s] + atomicAdd(&cursors[s], 1u);
        // pack row id (20 bits used) + segment-local id (6 bits)
        rowids[p] = (unsigned)i | ((unsigned)(s & (SEGS_PER_BLK - 1)) << 26);
    }
}

// ---------------- fused gather-MLP-reduce ----------------
// Block b owns segments [b*64, b*64+64). Rows arrive via CSR in sorted order.
// Swapped-operand MFMA: D = W^T * x^T so each lane owns one row's outputs.
__global__ __launch_bounds__(256) void mlp_gather_kernel(
    const float* __restrict__ vecs,
    const unsigned* __restrict__ rowids,
    const unsigned* __restrict__ offsets,
    const float* __restrict__ W1, const float* __restrict__ b1,
    const float* __restrict__ W2, const float* __restrict__ b2,
    float* __restrict__ out, int nseg)
{
    __shared__ __align__(16) __bf16 sW1T[MID_F][IN_F];   // 16 KB, W1T[n][k]
    __shared__ __align__(16) __bf16 sW2T[OUT_F][MID_F];  //  8 KB, W2T[n][k]
    __shared__ float sOsum[SEGS_PER_BLK][OUT_F + 1];     // +1 pad: bank spread
    __shared__ unsigned sOff[SEGS_PER_BLK + 1];

    const int tid = threadIdx.x;
    const int b = blockIdx.x;

    for (int i = tid; i < IN_F * MID_F; i += 256)
        sW1T[i & (MID_F - 1)][i >> 7] = (__bf16)W1[i];
    for (int i = tid; i < MID_F * OUT_F; i += 256)
        sW2T[i & (OUT_F - 1)][i >> 5] = (__bf16)W2[i];
    for (int i = tid; i < SEGS_PER_BLK * (OUT_F + 1); i += 256)
        ((float*)sOsum)[i] = 0.f;
    if (tid <= SEGS_PER_BLK) sOff[tid] = offsets[b * SEGS_PER_BLK + tid];
    __syncthreads();

    const int lane = tid & 63, wid = tid >> 6;
    const int lg = lane >> 4, lr = lane & 15;

    // Layer-1 A-operand: W1^T tiles. lane holds A[row=lr][k=q*32+lg*8+j].
    bf16x8 w1f[8][2];
    #pragma unroll
    for (int t = 0; t < 8; ++t)
        #pragma unroll
        for (int q = 0; q < 2; ++q)
            w1f[t][q] = *(const bf16x8*)&sW1T[t * 16 + lr][q * 32 + lg * 8];

    // Layer-2 A-operand: W2^T with custom k-map k = q*32 + 16*(j>>2) + 4*lg + (j&3)
    // (consistent with B = lane's own packed h tiles -> zero shuffles).
    bf16x8 w2f[2][4];
    #pragma unroll
    for (int u = 0; u < 2; ++u)
        #pragma unroll
        for (int q = 0; q < 4; ++q) {
            bf16x4 lo = *(const bf16x4*)&sW2T[u * 16 + lr][q * 32 + lg * 4];
            bf16x4 hi = *(const bf16x4*)&sW2T[u * 16 + lr][q * 32 + 16 + lg * 4];
            w2f[u][q] = __builtin_shufflevector(lo, hi, 0, 1, 2, 3, 4, 5, 6, 7);
        }

    // Biases for the features this lane owns in h^T / preds^T C-layout.
    float b1v[8][4];
    #pragma unroll
    for (int t = 0; t < 8; ++t)
        #pragma unroll
        for (int r = 0; r < 4; ++r) b1v[t][r] = b1[t * 16 + lg * 4 + r];
    float b2v[2][4];
    #pragma unroll
    for (int u = 0; u < 2; ++u)
        #pragma unroll
        for (int r = 0; r < 4; ++r) b2v[u][r] = b2[u * 16 + lg * 4 + r];

    const unsigned rowStart = sOff[0], rowEnd = sOff[SEGS_PER_BLK];
    const int nrowsB = (int)(rowEnd - rowStart);

    for (int ch = wid; ch * 16 < nrowsB; ch += 4) {
        const int base = (int)rowStart + ch * 16;
        const int myrow = base + lr;
        const bool valid = myrow < (int)rowEnd;
        const unsigned rw = rowids[valid ? myrow : (int)rowStart];
        const int rid = (int)(rw & 0x03FFFFFFu);
        const int segloc = (int)(rw >> 26);

        // Gather this row's x: 16 floats per lane (feats lg*8..+7 and +32).
        const float* xr = vecs + (size_t)rid * IN_F + lg * 8;
        f32x4 x0a = *(const f32x4*)(xr);
        f32x4 x0b = *(const f32x4*)(xr + 4);
        f32x4 x1a = *(const f32x4*)(xr + 32);
        f32x4 x1b = *(const f32x4*)(xr + 36);
        bf16x8 a[2];
        #pragma unroll
        for (int j = 0; j < 4; ++j) {
            a[0][j] = (__bf16)x0a[j]; a[0][j + 4] = (__bf16)x0b[j];
            a[1][j] = (__bf16)x1a[j]; a[1][j + 4] = (__bf16)x1b[j];
        }

        // Layer 1 (swapped): hT tiles; lane owns h[row lr][feat 16t+4lg+r].
        unsigned p[8][2];
        #pragma unroll
        for (int t = 0; t < 8; ++t) {
            f32x4 acc = { b1v[t][0], b1v[t][1], b1v[t][2], b1v[t][3] };
            acc = __builtin_amdgcn_mfma_f32_16x16x32_bf16(w1f[t][0], a[0], acc, 0, 0, 0);
            acc = __builtin_amdgcn_mfma_f32_16x16x32_bf16(w1f[t][1], a[1], acc, 0, 0, 0);
            p[t][0] = pack2(fmaxf(acc[0], 0.f), fmaxf(acc[1], 0.f));
            p[t][1] = pack2(fmaxf(acc[2], 0.f), fmaxf(acc[3], 0.f));
        }

        // Layer 2 (swapped): B_q = lane's own packed tiles (2q, 2q+1).
        f32x4 acc2[2];
        acc2[0] = { b2v[0][0], b2v[0][1], b2v[0][2], b2v[0][3] };
        acc2[1] = { b2v[1][0], b2v[1][1], b2v[1][2], b2v[1][3] };
        #pragma unroll
        for (int q = 0; q < 4; ++q) {
            int4 bi = make_int4((int)p[2 * q][0], (int)p[2 * q][1],
                                (int)p[2 * q + 1][0], (int)p[2 * q + 1][1]);
            bf16x8 B = __builtin_bit_cast(bf16x8, bi);
            acc2[0] = __builtin_amdgcn_mfma_f32_16x16x32_bf16(w2f[0][q], B, acc2[0], 0, 0, 0);
            acc2[1] = __builtin_amdgcn_mfma_f32_16x16x32_bf16(w2f[1][q], B, acc2[1], 0, 0, 0);
        }

        // Reduce into LDS per-segment sums (lane owns row lr's feats 16u+4lg+r).
        if (valid) {
            #pragma unroll
            for (int u = 0; u < 2; ++u)
                #pragma unroll
                for (int r = 0; r < 4; ++r)
                    atomicAdd(&sOsum[segloc][u * 16 + lg * 4 + r], acc2[u][r]);
        }
    }
    __syncthreads();

    // Write means; empty segments stay 0 (0 / max(0,1)).
    for (int i = tid; i < SEGS_PER_BLK * OUT_F; i += 256) {
        const int sl = i >> 5, f = i & 31;
        const int sg = b * SEGS_PER_BLK + sl;
        if (sg < nseg) {
            const float cnt = (float)(sOff[sl + 1] - sOff[sl]);
            out[(size_t)sg * OUT_F + f] = sOsum[sl][f] / fmaxf(cnt, 1.f);
        }
    }
}

extern "C" void kernel_launch(void* const* d_in, const int* in_sizes, int n_in,
                              void* d_out, int out_size, void* d_ws, size_t ws_size,
                              hipStream_t stream)
{
    const float* vecs = (const float*)d_in[0];
    const int*   sidx = (const int*)d_in[1];
    const float* W1 = (const float*)d_in[3];
    const float* b1 = (const float*)d_in[4];
    const float* W2 = (const float*)d_in[5];
    const float* b2 = (const float*)d_in[6];
    float* out = (float*)d_out;

    const int nrows = in_sizes[0] / IN_F;
    const int nseg  = out_size / OUT_F;
    const int nblk  = (nseg + SEGS_PER_BLK - 1) / SEGS_PER_BLK;
    const int nsegP = nblk * SEGS_PER_BLK;
    const int nsb   = (nsegP + 1023) / 1024;   // <= 1024 assumed

    auto algn = [](size_t x) { return (x + 255) & ~(size_t)255; };
    char* w = (char*)d_ws;
    unsigned* counts  = (unsigned*)w;                          // nsegP (reused as cursors)
    w += algn((size_t)nsegP * 4);
    unsigned* offsets = (unsigned*)w;                          // nsegP + 1
    w += algn((size_t)(nsegP + 1) * 4);
    unsigned* bsum    = (unsigned*)w;                          // nsb
    w += algn(1024 * 4);
    unsigned* rowids  = (unsigned*)w;                          // nrows

    hipMemsetAsync(counts, 0, (size_t)nsegP * 4, stream);
    hist_kernel<<<2048, 256, 0, stream>>>(sidx, counts, nrows);
    scan1_kernel<<<nsb, 1024, 0, stream>>>(counts, offsets, bsum, nsegP);
    scan2_kernel<<<1, 1024, 0, stream>>>(bsum, nsb);
    scan3_kernel<<<nsb, 1024, 0, stream>>>(offsets, bsum, nsegP, nrows);
    hipMemsetAsync(counts, 0, (size_t)nsegP * 4, stream);      // now cursors
    scatter_kernel<<<2048, 256, 0, stream>>>(sidx, offsets, counts, rowids, nrows);
    mlp_gather_kernel<<<nblk, 256, 0, stream>>>(vecs, rowids, offsets,
                                                W1, b1, W2, b2, out, nseg);
}

// Round 3
// 236.768 us; speedup vs baseline: 1.8171x; 1.8171x over previous
//
#include <hip/hip_runtime.h>
#include <hip/hip_fp16.h>

#define IN_F  64
#define MID_F 128
#define OUT_F 32
#define SEGS_PER_BLK 64

typedef __bf16 bf16x8 __attribute__((ext_vector_type(8)));
typedef __bf16 bf16x4 __attribute__((ext_vector_type(4)));
typedef float  f32x4  __attribute__((ext_vector_type(4)));

static __device__ inline unsigned pack2(float a, float b) {
    unsigned short x = __builtin_bit_cast(unsigned short, (__bf16)a);
    unsigned short y = __builtin_bit_cast(unsigned short, (__bf16)b);
    return (unsigned)x | ((unsigned)y << 16);
}
static __device__ inline unsigned pkh2(float a, float b) {
    __half2 h = __floats2half2_rn(a, b);
    return __builtin_bit_cast(unsigned, h);
}

// ---------------- CSR build ----------------
__global__ void hist_rank_kernel(const int* __restrict__ sidx, unsigned* __restrict__ counts,
                                 unsigned* __restrict__ ranks, int n) {
    int i = blockIdx.x * blockDim.x + threadIdx.x;
    int stride = gridDim.x * blockDim.x;
    for (; i < n; i += stride) ranks[i] = atomicAdd(&counts[sidx[i]], 1u);
}

__global__ void scan1_kernel(const unsigned* __restrict__ counts, unsigned* __restrict__ offsets,
                             unsigned* __restrict__ bsum, int nsegP) {
    __shared__ unsigned s[1024];
    const int t = threadIdx.x;
    const int idx = blockIdx.x * 1024 + t;
    unsigned v = (idx < nsegP) ? counts[idx] : 0u;
    s[t] = v; __syncthreads();
    for (int o = 1; o < 1024; o <<= 1) {
        unsigned u = (t >= o) ? s[t - o] : 0u;
        __syncthreads();
        s[t] += u;
        __syncthreads();
    }
    if (idx < nsegP) offsets[idx] = s[t] - v;       // exclusive
    if (t == 1023) bsum[blockIdx.x] = s[1023];      // block total
}

__global__ void scan2_kernel(unsigned* __restrict__ bsum, int nb) {
    __shared__ unsigned s[1024];
    const int t = threadIdx.x;
    unsigned v = (t < nb) ? bsum[t] : 0u;
    s[t] = v; __syncthreads();
    for (int o = 1; o < 1024; o <<= 1) {
        unsigned u = (t >= o) ? s[t - o] : 0u;
        __syncthreads();
        s[t] += u;
        __syncthreads();
    }
    if (t < nb) bsum[t] = s[t] - v;                 // exclusive, in place
}

__global__ void scan3_kernel(unsigned* __restrict__ offsets, const unsigned* __restrict__ bsum,
                             int nsegP, int nrows) {
    int idx = blockIdx.x * 1024 + threadIdx.x;
    if (idx < nsegP) offsets[idx] += bsum[blockIdx.x];
    if (blockIdx.x == 0 && threadIdx.x == 0) offsets[nsegP] = (unsigned)nrows;
}

// ---------------- streaming MLP, scatter preds to sorted position ----------------
// Coalesced read of vecs; swapped-operand MFMA (lane owns a row); each row's
// 32 preds leave as ONE 64B line-write to its sorted slot (no atomics).
// W2/b2 are column-permuted so a lane's 8 outputs are feature-contiguous.
__global__ __launch_bounds__(256) void mlp_pred_kernel(
    const float* __restrict__ vecs,
    const int*   __restrict__ sidx,
    const unsigned* __restrict__ ranks,
    const unsigned* __restrict__ offsets,
    const float* __restrict__ W1, const float* __restrict__ b1,
    const float* __restrict__ W2, const float* __restrict__ b2,
    __half* __restrict__ preds, int nrows)
{
    __shared__ __align__(16) __bf16 sW1T[MID_F][IN_F];   // 16 KB, W1T[n][k]
    __shared__ __align__(16) __bf16 sW2T[OUT_F][MID_F];  //  8 KB, permuted W2T[n'][k]

    const int tid = threadIdx.x;

    for (int i = tid; i < IN_F * MID_F; i += 256)
        sW1T[i & (MID_F - 1)][i >> 7] = (__bf16)W1[i];
    for (int i = tid; i < MID_F * OUT_F; i += 256) {
        const int n = i & (OUT_F - 1), k = i >> 5;
        // perm(n) = lg*8 + u*4 + r for n = u*16 + lg*4 + r
        const int pn = ((n >> 2) & 3) * 8 + (n >> 4) * 4 + (n & 3);
        sW2T[n][k] = (__bf16)W2[k * OUT_F + pn];
    }
    __syncthreads();

    const int lane = tid & 63, wid = tid >> 6;
    const int lg = lane >> 4, lr = lane & 15;

    // Layer-1 A-operand fragments (W1^T), resident in registers.
    bf16x8 w1f[8][2];
    #pragma unroll
    for (int t = 0; t < 8; ++t)
        #pragma unroll
        for (int q = 0; q < 2; ++q)
            w1f[t][q] = *(const bf16x8*)&sW1T[t * 16 + lr][q * 32 + lg * 8];

    // Layer-2 A-operand with custom k-map (consistent with lane-local h packing).
    bf16x8 w2f[2][4];
    #pragma unroll
    for (int u = 0; u < 2; ++u)
        #pragma unroll
        for (int q = 0; q < 4; ++q) {
            bf16x4 lo = *(const bf16x4*)&sW2T[u * 16 + lr][q * 32 + lg * 4];
            bf16x4 hi = *(const bf16x4*)&sW2T[u * 16 + lr][q * 32 + 16 + lg * 4];
            w2f[u][q] = __builtin_shufflevector(lo, hi, 0, 1, 2, 3, 4, 5, 6, 7);
        }

    float b1v[8][4];
    #pragma unroll
    for (int t = 0; t < 8; ++t)
        #pragma unroll
        for (int r = 0; r < 4; ++r) b1v[t][r] = b1[t * 16 + lg * 4 + r];
    // Permuted bias: lane's (u,r) output is actual feature lg*8 + u*4 + r.
    float b2v[2][4];
    #pragma unroll
    for (int u = 0; u < 2; ++u)
        #pragma unroll
        for (int r = 0; r < 4; ++r) b2v[u][r] = b2[lg * 8 + u * 4 + r];

    const int nchunk = nrows >> 4;
    for (int c = blockIdx.x * 4 + wid; c < nchunk; c += gridDim.x * 4) {
        const int base = c << 4;
        const int myrow = base + lr;

        // Coalesced x tile load (consecutive rows).
        const float* xr = vecs + (size_t)myrow * IN_F + lg * 8;
        f32x4 x0a = *(const f32x4*)(xr);
        f32x4 x0b = *(const f32x4*)(xr + 4);
        f32x4 x1a = *(const f32x4*)(xr + 32);
        f32x4 x1b = *(const f32x4*)(xr + 36);
        bf16x8 a[2];
        #pragma unroll
        for (int j = 0; j < 4; ++j) {
            a[0][j] = (__bf16)x0a[j]; a[0][j + 4] = (__bf16)x0b[j];
            a[1][j] = (__bf16)x1a[j]; a[1][j + 4] = (__bf16)x1b[j];
        }

        // Destination slot (independent loads; offsets table is L2-resident).
        const int seg = sidx[myrow];
        const unsigned pos = offsets[seg] + ranks[myrow];

        // Layer 1 (swapped): lane owns h[row lr][feat t*16+lg*4+r].
        unsigned p[8][2];
        #pragma unroll
        for (int t = 0; t < 8; ++t) {
            f32x4 acc = { b1v[t][0], b1v[t][1], b1v[t][2], b1v[t][3] };
            acc = __builtin_amdgcn_mfma_f32_16x16x32_bf16(w1f[t][0], a[0], acc, 0, 0, 0);
            acc = __builtin_amdgcn_mfma_f32_16x16x32_bf16(w1f[t][1], a[1], acc, 0, 0, 0);
            p[t][0] = pack2(fmaxf(acc[0], 0.f), fmaxf(acc[1], 0.f));
            p[t][1] = pack2(fmaxf(acc[2], 0.f), fmaxf(acc[3], 0.f));
        }

        // Layer 2 (swapped, zero-shuffle).
        f32x4 acc2[2];
        acc2[0] = { b2v[0][0], b2v[0][1], b2v[0][2], b2v[0][3] };
        acc2[1] = { b2v[1][0], b2v[1][1], b2v[1][2], b2v[1][3] };
        #pragma unroll
        for (int q = 0; q < 4; ++q) {
            int4 bi = make_int4((int)p[2 * q][0], (int)p[2 * q][1],
                                (int)p[2 * q + 1][0], (int)p[2 * q + 1][1]);
            bf16x8 B = __builtin_bit_cast(bf16x8, bi);
            acc2[0] = __builtin_amdgcn_mfma_f32_16x16x32_bf16(w2f[0][q], B, acc2[0], 0, 0, 0);
            acc2[1] = __builtin_amdgcn_mfma_f32_16x16x32_bf16(w2f[1][q], B, acc2[1], 0, 0, 0);
        }

        // One 16B store per lane; 4 lanes complete the row's 64B line.
        int4 st;
        st.x = (int)pkh2(acc2[0][0], acc2[0][1]);
        st.y = (int)pkh2(acc2[0][2], acc2[0][3]);
        st.z = (int)pkh2(acc2[1][0], acc2[1][1]);
        st.w = (int)pkh2(acc2[1][2], acc2[1][3]);
        *(int4*)(preds + (size_t)pos * OUT_F + lg * 8) = st;
    }
}

// ---------------- coalesced segment mean ----------------
__global__ __launch_bounds__(256) void seg_reduce_kernel(
    const __half* __restrict__ preds,
    const unsigned* __restrict__ offsets,
    float* __restrict__ out, int nseg)
{
    const int tid = threadIdx.x;
    const int lane = tid & 63, wid = tid >> 6;
    const int fp = lane & 15;   // feature pair 0..15
    const int ro = lane >> 4;   // row offset 0..3

    for (int s = wid; s < SEGS_PER_BLK; s += 4) {
        const int gs = blockIdx.x * SEGS_PER_BLK + s;
        if (gs >= nseg) continue;
        const unsigned o0 = offsets[gs], o1 = offsets[gs + 1];

        float a0 = 0.f, a1 = 0.f;
        for (unsigned r = o0 + ro; r < o1; r += 4) {
            __half2 h = *(const __half2*)(preds + (size_t)r * OUT_F + fp * 2);
            float2 f = __half22float2(h);
            a0 += f.x; a1 += f.y;
        }
        a0 += __shfl_xor(a0, 16); a1 += __shfl_xor(a1, 16);
        a0 += __shfl_xor(a0, 32); a1 += __shfl_xor(a1, 32);
        if (lane < 16) {
            const float inv = 1.f / fmaxf((float)(o1 - o0), 1.f);
            *(float2*)(out + (size_t)gs * OUT_F + fp * 2) = make_float2(a0 * inv, a1 * inv);
        }
    }
}

// ---------------- fallback (direct global atomics, round-1 proven) ----------------
__global__ __launch_bounds__(256) void fb_mlp_scatter(
    const float* __restrict__ vecs, const int* __restrict__ sidx,
    const float* __restrict__ W1, const float* __restrict__ b1,
    const float* __restrict__ W2, const float* __restrict__ b2,
    float* __restrict__ osum, float* __restrict__ counts, int nrows)
{
    __shared__ __align__(16) __bf16 sW1T[MID_F][IN_F];
    __shared__ __align__(16) __bf16 sW2T[OUT_F][MID_F];
    const int tid = threadIdx.x;
    for (int i = tid; i < IN_F * MID_F; i += 256)
        sW1T[i & (MID_F - 1)][i >> 7] = (__bf16)W1[i];
    for (int i = tid; i < MID_F * OUT_F; i += 256)
        sW2T[i & (OUT_F - 1)][i >> 5] = (__bf16)W2[i];
    __syncthreads();
    const int lane = tid & 63, wid = tid >> 6, lg = lane >> 4, lr = lane & 15;
    bf16x8 w1f[8][2];
    for (int t = 0; t < 8; ++t)
        for (int q = 0; q < 2; ++q)
            w1f[t][q] = *(const bf16x8*)&sW1T[t * 16 + lr][q * 32 + lg * 8];
    bf16x8 w2f[2][4];
    for (int u = 0; u < 2; ++u)
        for (int q = 0; q < 4; ++q) {
            bf16x4 lo = *(const bf16x4*)&sW2T[u * 16 + lr][q * 32 + lg * 4];
            bf16x4 hi = *(const bf16x4*)&sW2T[u * 16 + lr][q * 32 + 16 + lg * 4];
            w2f[u][q] = __builtin_shufflevector(lo, hi, 0, 1, 2, 3, 4, 5, 6, 7);
        }
    float b1v[8][4], b2v[2][4];
    for (int t = 0; t < 8; ++t)
        for (int r = 0; r < 4; ++r) b1v[t][r] = b1[t * 16 + lg * 4 + r];
    for (int u = 0; u < 2; ++u)
        for (int r = 0; r < 4; ++r) b2v[u][r] = b2[u * 16 + lg * 4 + r];
    const int nchunk = nrows >> 4;
    for (int c = blockIdx.x * 4 + wid; c < nchunk; c += gridDim.x * 4) {
        const int base = c << 4, myrow = base + lr;
        const float* xr = vecs + (size_t)myrow * IN_F + lg * 8;
        f32x4 x0a = *(const f32x4*)(xr), x0b = *(const f32x4*)(xr + 4);
        f32x4 x1a = *(const f32x4*)(xr + 32), x1b = *(const f32x4*)(xr + 36);
        bf16x8 a[2];
        for (int j = 0; j < 4; ++j) {
            a[0][j] = (__bf16)x0a[j]; a[0][j + 4] = (__bf16)x0b[j];
            a[1][j] = (__bf16)x1a[j]; a[1][j + 4] = (__bf16)x1b[j];
        }
        unsigned p[8][2];
        for (int t = 0; t < 8; ++t) {
            f32x4 acc = { b1v[t][0], b1v[t][1], b1v[t][2], b1v[t][3] };
            acc = __builtin_amdgcn_mfma_f32_16x16x32_bf16(w1f[t][0], a[0], acc, 0, 0, 0);
            acc = __builtin_amdgcn_mfma_f32_16x16x32_bf16(w1f[t][1], a[1], acc, 0, 0, 0);
            p[t][0] = pack2(fmaxf(acc[0], 0.f), fmaxf(acc[1], 0.f));
            p[t][1] = pack2(fmaxf(acc[2], 0.f), fmaxf(acc[3], 0.f));
        }
        f32x4 acc2[2];
        acc2[0] = { b2v[0][0], b2v[0][1], b2v[0][2], b2v[0][3] };
        acc2[1] = { b2v[1][0], b2v[1][1], b2v[1][2], b2v[1][3] };
        for (int q = 0; q < 4; ++q) {
            int4 bi = make_int4((int)p[2 * q][0], (int)p[2 * q][1],
                                (int)p[2 * q + 1][0], (int)p[2 * q + 1][1]);
            bf16x8 B = __builtin_bit_cast(bf16x8, bi);
            acc2[0] = __builtin_amdgcn_mfma_f32_16x16x32_bf16(w2f[0][q], B, acc2[0], 0, 0, 0);
            acc2[1] = __builtin_amdgcn_mfma_f32_16x16x32_bf16(w2f[1][q], B, acc2[1], 0, 0, 0);
        }
        const int seg = sidx[myrow];
        float* o = osum + (size_t)seg * OUT_F;
        for (int u = 0; u < 2; ++u)
            for (int r = 0; r < 4; ++r)
                atomicAdd(o + u * 16 + lg * 4 + r, acc2[u][r]);
        if (lg == 0) atomicAdd(counts + seg, 1.0f);
    }
}

__global__ __launch_bounds__(256) void fb_finalize(
    float* __restrict__ osum, const float* __restrict__ counts, int total)
{
    int i = blockIdx.x * 256 + threadIdx.x;
    if (i < total) osum[i] = osum[i] / fmaxf(counts[i >> 5], 1.0f);
}

extern "C" void kernel_launch(void* const* d_in, const int* in_sizes, int n_in,
                              void* d_out, int out_size, void* d_ws, size_t ws_size,
                              hipStream_t stream)
{
    const float* vecs = (const float*)d_in[0];
    const int*   sidx = (const int*)d_in[1];
    const float* W1 = (const float*)d_in[3];
    const float* b1 = (const float*)d_in[4];
    const float* W2 = (const float*)d_in[5];
    const float* b2 = (const float*)d_in[6];
    float* out = (float*)d_out;

    const int nrows = in_sizes[0] / IN_F;
    const int nseg  = out_size / OUT_F;
    const int nblk  = (nseg + SEGS_PER_BLK - 1) / SEGS_PER_BLK;
    const int nsegP = nblk * SEGS_PER_BLK;
    const int nsb   = (nsegP + 1023) / 1024;   // <= 1024 assumed

    auto algn = [](size_t x) { return (x + 255) & ~(size_t)255; };
    size_t off_counts = 0;
    size_t off_offs   = off_counts + algn((size_t)nsegP * 4);
    size_t off_bsum   = off_offs   + algn((size_t)(nsegP + 1) * 4);
    size_t off_ranks  = off_bsum   + algn(1024 * 4);
    size_t off_preds  = off_ranks  + algn((size_t)nrows * 4);
    size_t need       = off_preds  + (size_t)nrows * OUT_F * sizeof(__half);

    if (ws_size < need) {
        // Fallback: direct-atomic path (correct, slower).
        float* osum   = out;
        float* counts = (float*)d_ws;
        hipMemsetAsync(osum, 0, (size_t)out_size * sizeof(float), stream);
        hipMemsetAsync(counts, 0, (size_t)nseg * sizeof(float), stream);
        fb_mlp_scatter<<<2048, 256, 0, stream>>>(vecs, sidx, W1, b1, W2, b2,
                                                 osum, counts, nrows);
        fb_finalize<<<(out_size + 255) / 256, 256, 0, stream>>>(osum, counts, out_size);
        return;
    }

    char* w = (char*)d_ws;
    unsigned* counts  = (unsigned*)(w + off_counts);
    unsigned* offsets = (unsigned*)(w + off_offs);
    unsigned* bsum    = (unsigned*)(w + off_bsum);
    unsigned* ranks   = (unsigned*)(w + off_ranks);
    __half*   preds   = (__half*)(w + off_preds);

    hipMemsetAsync(counts, 0, (size_t)nsegP * 4, stream);
    hist_rank_kernel<<<1024, 256, 0, stream>>>(sidx, counts, ranks, nrows);
    scan1_kernel<<<nsb, 1024, 0, stream>>>(counts, offsets, bsum, nsegP);
    scan2_kernel<<<1, 1024, 0, stream>>>(bsum, nsb);
    scan3_kernel<<<nsb, 1024, 0, stream>>>(offsets, bsum, nsegP, nrows);
    mlp_pred_kernel<<<2048, 256, 0, stream>>>(vecs, sidx, ranks, offsets,
                                              W1, b1, W2, b2, preds, nrows);
    seg_reduce_kernel<<<nblk, 256, 0, stream>>>(preds, offsets, out, nseg);
}